// Round 1
// baseline (1878.711 us; speedup 1.0000x reference)
//
#include <hip/hip_runtime.h>
#include <math.h>

#define IN_DIM 1433
#define H_TOPO 64
#define ALIGN 32
#define NCLS 7

// ---------------- degree init / count / rsqrt ----------------

__global__ void k_init(float* __restrict__ deg, int n) {
    int i = blockIdx.x * blockDim.x + threadIdx.x;
    if (i < n) deg[i] = 1.0f;  // self-loop
}

__global__ void k_count(const int* __restrict__ ei, float* __restrict__ deg, int E) {
    int e = blockIdx.x * blockDim.x + threadIdx.x;
    if (e < E) atomicAdd(&deg[ei[E + e]], 1.0f);
}

__global__ void k_rsqrt(const float* __restrict__ deg, float* __restrict__ dis, int n) {
    int i = blockIdx.x * blockDim.x + threadIdx.x;
    if (i < n) dis[i] = rsqrtf(deg[i]);
}

// ---------------- fused GEMM: xw = x@W_gcn ; z_sem = x@W_ps + b_ps ----------------
// Also writes agg = xw * dis^2  (self-loop term) so agg needs no zero-init.

#define BM 128
#define BK 32
#define BN 96   // 64 (W_gcn) + 32 (W_ps)

__global__ __launch_bounds__(256) void k_gemm(
    const float* __restrict__ x, const float* __restrict__ Wg,
    const float* __restrict__ Wp, const float* __restrict__ bps,
    const float* __restrict__ dis,
    float* __restrict__ xw, float* __restrict__ agg, float* __restrict__ zsem,
    int n)
{
    __shared__ float xs[BM][BK + 1];
    __shared__ float wt[BK][BN];
    int t = threadIdx.x;
    int tx = t & 15;        // col group: 6 cols each -> 96
    int ty = t >> 4;        // row group: 8 rows each -> 128
    long row0 = (long)blockIdx.x * BM;

    float acc[8][6] = {};

    for (int k0 = 0; k0 < IN_DIM; k0 += BK) {
        // stage x tile [128 x 32]
        #pragma unroll
        for (int l = 0; l < 16; ++l) {
            int idx = l * 256 + t;
            int r = idx >> 5, c = idx & 31;
            long gr = row0 + r; int gc = k0 + c;
            xs[r][c] = (gr < n && gc < IN_DIM) ? x[gr * IN_DIM + gc] : 0.0f;
        }
        // stage W tile [32 x 96]
        #pragma unroll
        for (int l = 0; l < 12; ++l) {
            int idx = l * 256 + t;
            int k = idx / 96, c = idx % 96;
            int gk = k0 + k;
            float v = 0.0f;
            if (gk < IN_DIM) v = (c < 64) ? Wg[gk * 64 + c] : Wp[gk * 32 + (c - 64)];
            wt[k][c] = v;
        }
        __syncthreads();
        #pragma unroll
        for (int kk = 0; kk < BK; ++kk) {
            float a[8], b[6];
            #pragma unroll
            for (int r = 0; r < 8; ++r) a[r] = xs[ty * 8 + r][kk];
            #pragma unroll
            for (int j = 0; j < 6; ++j) b[j] = wt[kk][tx * 6 + j];
            #pragma unroll
            for (int r = 0; r < 8; ++r)
                #pragma unroll
                for (int j = 0; j < 6; ++j)
                    acc[r][j] += a[r] * b[j];
        }
        __syncthreads();
    }

    #pragma unroll
    for (int r = 0; r < 8; ++r) {
        long grow = row0 + ty * 8 + r;
        if (grow >= n) continue;
        float d = dis[grow];
        float d2 = d * d;
        #pragma unroll
        for (int j = 0; j < 6; ++j) {
            int c = tx * 6 + j;
            float v = acc[r][j];
            if (c < 64) {
                xw[grow * 64 + c]  = v;
                agg[grow * 64 + c] = v * d2;   // self-loop message
            } else {
                zsem[grow * 32 + (c - 64)] = v + bps[c - 64];
            }
        }
    }
}

// ---------------- edge scatter: agg[dst] += xw[src] * dis[src]*dis[dst] ----------------
// one wave per edge; lane = feature (64 features = 64 lanes)

__global__ __launch_bounds__(256) void k_scatter(
    const int* __restrict__ ei, const float* __restrict__ xw,
    const float* __restrict__ dis, float* __restrict__ agg, int E)
{
    long gid = (long)blockIdx.x * blockDim.x + threadIdx.x;
    int e = (int)(gid >> 6);
    int lane = (int)(gid & 63);
    if (e >= E) return;
    int src = ei[e];
    int dst = ei[E + e];
    float norm = dis[src] * dis[dst];
    atomicAdd(&agg[(long)dst * 64 + lane], xw[(long)src * 64 + lane] * norm);
}

// ---------------- per-node head ----------------
// h = relu(agg + b_gcn); z_topo = h@W_pt + b_pt; logits = z_topo@W_cls + b_cls;
// anomaly = ||z_topo - z_sem||

__global__ __launch_bounds__(256) void k_head(
    const float* __restrict__ agg, const float* __restrict__ bgcn,
    const float* __restrict__ Wpt, const float* __restrict__ bpt,
    const float* __restrict__ Wcls, const float* __restrict__ bcls,
    const float* __restrict__ zsem,
    float* __restrict__ logits, float* __restrict__ anom, float* __restrict__ ztopo,
    int n)
{
    __shared__ float sW[H_TOPO * ALIGN];
    __shared__ float sC[ALIGN * NCLS];
    __shared__ float sbp[ALIGN], sbc[NCLS], sbg[H_TOPO];
    int t = threadIdx.x;
    for (int i = t; i < H_TOPO * ALIGN; i += 256) sW[i] = Wpt[i];
    for (int i = t; i < ALIGN * NCLS; i += 256) sC[i] = Wcls[i];
    if (t < ALIGN) sbp[t] = bpt[t];
    if (t < NCLS) sbc[t] = bcls[t];
    if (t < H_TOPO) sbg[t] = bgcn[t];
    __syncthreads();

    long node = (long)blockIdx.x * 256 + t;
    if (node >= n) return;

    float h[H_TOPO];
    const float* arow = agg + node * H_TOPO;
    #pragma unroll
    for (int k = 0; k < H_TOPO; ++k) h[k] = fmaxf(arow[k] + sbg[k], 0.0f);

    float z[ALIGN];
    #pragma unroll
    for (int j = 0; j < ALIGN; ++j) z[j] = sbp[j];
    #pragma unroll 4
    for (int k = 0; k < H_TOPO; ++k) {
        float hk = h[k];
        #pragma unroll
        for (int j = 0; j < ALIGN; ++j) z[j] += hk * sW[k * ALIGN + j];
    }

    float lg[NCLS];
    #pragma unroll
    for (int c = 0; c < NCLS; ++c) lg[c] = sbc[c];
    #pragma unroll
    for (int j = 0; j < ALIGN; ++j) {
        float zj = z[j];
        #pragma unroll
        for (int c = 0; c < NCLS; ++c) lg[c] += zj * sC[j * NCLS + c];
    }

    float ss = 0.0f;
    const float* zs = zsem + node * ALIGN;
    #pragma unroll
    for (int j = 0; j < ALIGN; ++j) { float d = z[j] - zs[j]; ss += d * d; }

    #pragma unroll
    for (int c = 0; c < NCLS; ++c) logits[node * NCLS + c] = lg[c];
    anom[node] = sqrtf(ss);
    #pragma unroll
    for (int j = 0; j < ALIGN; ++j) ztopo[node * ALIGN + j] = z[j];
}

// ---------------- launch ----------------

extern "C" void kernel_launch(void* const* d_in, const int* in_sizes, int n_in,
                              void* d_out, int out_size, void* d_ws, size_t ws_size,
                              hipStream_t stream) {
    const float* x   = (const float*)d_in[0];
    const int*   ei  = (const int*)d_in[1];
    const float* Wg  = (const float*)d_in[2];
    const float* bg  = (const float*)d_in[3];
    const float* Wpt = (const float*)d_in[4];
    const float* bpt = (const float*)d_in[5];
    const float* Wps = (const float*)d_in[6];
    const float* bps = (const float*)d_in[7];
    const float* Wc  = (const float*)d_in[8];
    const float* bc  = (const float*)d_in[9];

    int n = in_sizes[0] / IN_DIM;   // 50000
    int E = in_sizes[1] / 2;        // 1600000

    float* out    = (float*)d_out;
    float* logits = out;                        // n*7
    float* anom   = logits + (long)n * NCLS;    // n
    float* ztopo  = anom + n;                   // n*32
    float* zsem   = ztopo + (long)n * ALIGN;    // n*32

    float* ws  = (float*)d_ws;
    float* xw  = ws;                            // n*64
    float* agg = xw + (long)n * H_TOPO;         // n*64
    float* deg = agg + (long)n * H_TOPO;        // n
    float* dis = deg + n;                       // n

    k_init<<<(n + 255) / 256, 256, 0, stream>>>(deg, n);
    k_count<<<(E + 255) / 256, 256, 0, stream>>>(ei, deg, E);
    k_rsqrt<<<(n + 255) / 256, 256, 0, stream>>>(deg, dis, n);
    k_gemm<<<(n + BM - 1) / BM, 256, 0, stream>>>(x, Wg, Wps, bps, dis, xw, agg, zsem, n);
    long tot = (long)E * 64;
    k_scatter<<<(int)((tot + 255) / 256), 256, 0, stream>>>(ei, xw, dis, agg, E);
    k_head<<<(n + 255) / 256, 256, 0, stream>>>(agg, bg, Wpt, bpt, Wc, bc, zsem,
                                                logits, anom, ztopo, n);
}

// Round 2
// 1031.535 us; speedup vs baseline: 1.8213x; 1.8213x over previous
//
#include <hip/hip_runtime.h>
#include <math.h>

#define IN_DIM 1433
#define KPAD 1472          // 23 * 64, zero-padded
#define H_TOPO 64
#define ALIGN 32
#define NCLS 7

typedef __attribute__((ext_vector_type(8))) short short8;
typedef __attribute__((ext_vector_type(4))) float floatx4;

__device__ inline unsigned short f2bf(float f) {
    union { float f; unsigned u; } v; v.f = f;
    unsigned r = v.u + 0x7FFF + ((v.u >> 16) & 1);   // round-to-nearest-even
    return (unsigned short)(r >> 16);
}

// ---------------- degree init / count / rsqrt ----------------

__global__ void k_init(float* __restrict__ deg, int n) {
    int i = blockIdx.x * blockDim.x + threadIdx.x;
    if (i < n) deg[i] = 1.0f;  // self-loop
}

__global__ void k_count(const int* __restrict__ ei, float* __restrict__ deg, int E) {
    int e = blockIdx.x * blockDim.x + threadIdx.x;
    if (e < E) atomicAdd(&deg[ei[E + e]], 1.0f);
}

__global__ void k_rsqrt(const float* __restrict__ deg, float* __restrict__ dis, int n) {
    int i = blockIdx.x * blockDim.x + threadIdx.x;
    if (i < n) dis[i] = rsqrtf(deg[i]);
}

// ---------------- W pre-transpose to bf16: wT[c][k], c in 0..95, k padded ----------------

__global__ void k_wprep(const float* __restrict__ Wg, const float* __restrict__ Wp,
                        unsigned short* __restrict__ wT) {
    int i = blockIdx.x * blockDim.x + threadIdx.x;
    if (i >= 96 * KPAD) return;
    int c = i / KPAD, k = i % KPAD;
    float v = 0.0f;
    if (k < IN_DIM) v = (c < 64) ? Wg[k * 64 + c] : Wp[k * 32 + (c - 64)];
    wT[i] = f2bf(v);
}

// ---------------- MFMA GEMM: xws = (x@W_gcn)*dis ; agg = xw*dis^2 ; zsem = x@W_ps + b_ps ----

#define BM 64
#define BK 64
#define APAD 72    // LDS row stride in ushorts (144 B = 36 banks -> conflict-free quads)

__global__ __launch_bounds__(256) void k_gemm(
    const float* __restrict__ x, const unsigned short* __restrict__ wT,
    const float* __restrict__ bps, const float* __restrict__ dis,
    float* __restrict__ xws, float* __restrict__ agg, float* __restrict__ zsem,
    int n)
{
    __shared__ unsigned short a_lds[BM * APAD];   // 9216 B
    __shared__ unsigned short b_lds[96 * APAD];   // 13824 B

    int t = threadIdx.x;
    int row0 = blockIdx.x * BM;
    int w  = t >> 6;        // wave 0..3 -> rows w*16..w*16+15
    int l  = t & 63;
    int lm = l & 15;
    int lg = l >> 4;

    floatx4 acc[6] = {};    // 6 x (16x16) tiles covering 96 cols

    int ar = t >> 6;        // staging: 4 rows per pass
    int ak = t & 63;

    for (int k0 = 0; k0 < IN_DIM; k0 += BK) {
        // stage A: 64 rows x 64 k, fp32 -> bf16 (coalesced 64-wide dword loads)
        #pragma unroll
        for (int rr = 0; rr < BM; rr += 4) {
            int r  = rr + ar;
            int gr = row0 + r;
            int gk = k0 + ak;
            float v = (gr < n && gk < IN_DIM) ? x[(long)gr * IN_DIM + gk] : 0.0f;
            a_lds[r * APAD + ak] = f2bf(v);
        }
        // stage B: 96 rows x 64 k from pre-converted wT (16B chunks, all L2-hit)
        #pragma unroll
        for (int it = 0; it < 3; ++it) {
            int idx = it * 256 + t;          // 0..767
            int c   = idx >> 3;              // 0..95
            int kc  = (idx & 7) * 8;         // 0..56
            short8 v = *(const short8*)&wT[c * KPAD + k0 + kc];
            *(short8*)&b_lds[c * APAD + kc] = v;
        }
        __syncthreads();
        #pragma unroll
        for (int h = 0; h < 2; ++h) {
            int koff = h * 32 + lg * 8;
            short8 af = *(const short8*)&a_lds[(w * 16 + lm) * APAD + koff];
            #pragma unroll
            for (int j = 0; j < 6; ++j) {
                short8 bf = *(const short8*)&b_lds[(j * 16 + lm) * APAD + koff];
                acc[j] = __builtin_amdgcn_mfma_f32_16x16x32_bf16(af, bf, acc[j], 0, 0, 0);
            }
        }
        __syncthreads();
    }

    // epilogue: C layout col=lane&15, row=(lane>>4)*4+reg
    #pragma unroll
    for (int r = 0; r < 4; ++r) {
        int grow = row0 + w * 16 + lg * 4 + r;
        if (grow >= n) continue;
        float d = dis[grow];
        #pragma unroll
        for (int j = 0; j < 6; ++j) {
            int c = j * 16 + lm;
            float v = acc[j][r];
            if (c < 64) {
                float s = v * d;                       // xw * dis  (pre-scaled for scatter)
                xws[(long)grow * 64 + c] = s;
                agg[(long)grow * 64 + c] = s * d;      // self-loop msg: xw * dis^2
            } else {
                zsem[(long)grow * 32 + (c - 64)] = v + bps[c - 64];
            }
        }
    }
}

// ---------------- edge scatter: agg[dst] += xws[src] * dis[dst] ----------------

__global__ __launch_bounds__(256) void k_scatter(
    const int* __restrict__ ei, const float* __restrict__ xws,
    const float* __restrict__ dis, float* __restrict__ agg, int E)
{
    long gid = (long)blockIdx.x * blockDim.x + threadIdx.x;
    int e = (int)(gid >> 6);
    int lane = (int)(gid & 63);
    if (e >= E) return;
    int src = ei[e];
    int dst = ei[E + e];
    float dd = dis[dst];
    atomicAdd(&agg[(long)dst * 64 + lane], xws[(long)src * 64 + lane] * dd);
}

// ---------------- per-node head ----------------

__global__ __launch_bounds__(256) void k_head(
    const float* __restrict__ agg, const float* __restrict__ bgcn,
    const float* __restrict__ Wpt, const float* __restrict__ bpt,
    const float* __restrict__ Wcls, const float* __restrict__ bcls,
    const float* __restrict__ zsem,
    float* __restrict__ logits, float* __restrict__ anom, float* __restrict__ ztopo,
    int n)
{
    __shared__ float sW[H_TOPO * ALIGN];
    __shared__ float sC[ALIGN * NCLS];
    __shared__ float sbp[ALIGN], sbc[NCLS], sbg[H_TOPO];
    int t = threadIdx.x;
    for (int i = t; i < H_TOPO * ALIGN; i += 256) sW[i] = Wpt[i];
    for (int i = t; i < ALIGN * NCLS; i += 256) sC[i] = Wcls[i];
    if (t < ALIGN) sbp[t] = bpt[t];
    if (t < NCLS) sbc[t] = bcls[t];
    if (t < H_TOPO) sbg[t] = bgcn[t];
    __syncthreads();

    long node = (long)blockIdx.x * 256 + t;
    if (node >= n) return;

    float h[H_TOPO];
    const float* arow = agg + node * H_TOPO;
    #pragma unroll
    for (int k = 0; k < H_TOPO; ++k) h[k] = fmaxf(arow[k] + sbg[k], 0.0f);

    float z[ALIGN];
    #pragma unroll
    for (int j = 0; j < ALIGN; ++j) z[j] = sbp[j];
    #pragma unroll 4
    for (int k = 0; k < H_TOPO; ++k) {
        float hk = h[k];
        #pragma unroll
        for (int j = 0; j < ALIGN; ++j) z[j] += hk * sW[k * ALIGN + j];
    }

    float lg[NCLS];
    #pragma unroll
    for (int c = 0; c < NCLS; ++c) lg[c] = sbc[c];
    #pragma unroll
    for (int j = 0; j < ALIGN; ++j) {
        float zj = z[j];
        #pragma unroll
        for (int c = 0; c < NCLS; ++c) lg[c] += zj * sC[j * NCLS + c];
    }

    float ss = 0.0f;
    const float* zs = zsem + node * ALIGN;
    #pragma unroll
    for (int j = 0; j < ALIGN; ++j) { float d = z[j] - zs[j]; ss += d * d; }

    #pragma unroll
    for (int c = 0; c < NCLS; ++c) logits[node * NCLS + c] = lg[c];
    anom[node] = sqrtf(ss);
    #pragma unroll
    for (int j = 0; j < ALIGN; ++j) ztopo[node * ALIGN + j] = z[j];
}

// ---------------- launch ----------------

extern "C" void kernel_launch(void* const* d_in, const int* in_sizes, int n_in,
                              void* d_out, int out_size, void* d_ws, size_t ws_size,
                              hipStream_t stream) {
    const float* x   = (const float*)d_in[0];
    const int*   ei  = (const int*)d_in[1];
    const float* Wg  = (const float*)d_in[2];
    const float* bg  = (const float*)d_in[3];
    const float* Wpt = (const float*)d_in[4];
    const float* bpt = (const float*)d_in[5];
    const float* Wps = (const float*)d_in[6];
    const float* bps = (const float*)d_in[7];
    const float* Wc  = (const float*)d_in[8];
    const float* bc  = (const float*)d_in[9];

    int n = in_sizes[0] / IN_DIM;   // 50000
    int E = in_sizes[1] / 2;        // 1600000

    float* out    = (float*)d_out;
    float* logits = out;                        // n*7
    float* anom   = logits + (long)n * NCLS;    // n
    float* ztopo  = anom + n;                   // n*32
    float* zsem   = ztopo + (long)n * ALIGN;    // n*32

    float* ws  = (float*)d_ws;
    float* xws = ws;                            // n*64  (xw * dis)
    float* agg = xws + (long)n * H_TOPO;        // n*64
    float* deg = agg + (long)n * H_TOPO;        // n
    float* dis = deg + n;                       // n
    unsigned short* wT = (unsigned short*)(dis + n);  // 96*KPAD bf16 (16B-aligned: 130n*4 % 16 == 0)

    k_init<<<(n + 255) / 256, 256, 0, stream>>>(deg, n);
    k_count<<<(E + 255) / 256, 256, 0, stream>>>(ei, deg, E);
    k_rsqrt<<<(n + 255) / 256, 256, 0, stream>>>(deg, dis, n);
    k_wprep<<<(96 * KPAD + 255) / 256, 256, 0, stream>>>(Wg, Wps, wT);
    k_gemm<<<(n + BM - 1) / BM, 256, 0, stream>>>(x, wT, bps, dis, xws, agg, zsem, n);
    long tot = (long)E * 64;
    k_scatter<<<(int)((tot + 255) / 256), 256, 0, stream>>>(ei, xws, dis, agg, E);
    k_head<<<(n + 255) / 256, 256, 0, stream>>>(agg, bg, Wpt, bpt, Wc, bc, zsem,
                                                logits, anom, ztopo, n);
}

// Round 3
// 721.170 us; speedup vs baseline: 2.6051x; 1.4304x over previous
//
#include <hip/hip_runtime.h>
#include <math.h>

#define IN_DIM 1433
#define KPAD 1472          // 23 * 64, zero-padded
#define H_TOPO 64
#define ALIGN 32
#define NCLS 7

typedef __attribute__((ext_vector_type(8))) short short8;
typedef __attribute__((ext_vector_type(4))) short short4v;
typedef __attribute__((ext_vector_type(4))) float floatx4;
typedef float float4u __attribute__((ext_vector_type(4), aligned(4)));  // 4B-aligned float4

__device__ inline unsigned short f2bf(float f) {
    union { float f; unsigned u; } v; v.f = f;
    unsigned r = v.u + 0x7FFF + ((v.u >> 16) & 1);   // round-to-nearest-even
    return (unsigned short)(r >> 16);
}

// ---------------- degree histogram (int) + rsqrt ----------------

__global__ void k_init(int* __restrict__ cnt, int n) {
    int i = blockIdx.x * blockDim.x + threadIdx.x;
    if (i < n) cnt[i] = 0;
}

__global__ void k_count(const int* __restrict__ ei, int* __restrict__ cnt, int E) {
    int e = blockIdx.x * blockDim.x + threadIdx.x;
    if (e < E) atomicAdd(&cnt[ei[E + e]], 1);
}

__global__ void k_rsqrt(const int* __restrict__ cnt, float* __restrict__ dis, int n) {
    int i = blockIdx.x * blockDim.x + threadIdx.x;
    if (i < n) dis[i] = rsqrtf(1.0f + (float)cnt[i]);   // +1 self-loop
}

// ---------------- exclusive scan of cnt -> row_start (3 kernels) ----------------

__global__ void k_scan1(const int* __restrict__ cnt, int* __restrict__ part,
                        int* __restrict__ bsum, int n) {
    __shared__ int s[256];
    int t = threadIdx.x;
    int i = blockIdx.x * 256 + t;
    int v = (i < n) ? cnt[i] : 0;
    s[t] = v;
    __syncthreads();
    #pragma unroll
    for (int off = 1; off < 256; off <<= 1) {
        int x = (t >= off) ? s[t - off] : 0;
        __syncthreads();
        s[t] += x;
        __syncthreads();
    }
    if (i < n) part[i] = s[t] - v;          // exclusive within block
    if (t == 255) bsum[blockIdx.x] = s[255];
}

__global__ void k_scan2(int* __restrict__ bsum, int nb) {
    __shared__ int s[256];
    int t = threadIdx.x;
    int v = (t < nb) ? bsum[t] : 0;
    s[t] = v;
    __syncthreads();
    #pragma unroll
    for (int off = 1; off < 256; off <<= 1) {
        int x = (t >= off) ? s[t - off] : 0;
        __syncthreads();
        s[t] += x;
        __syncthreads();
    }
    if (t < nb) bsum[t] = s[t] - v;         // exclusive block offsets
}

__global__ void k_scan3(int* __restrict__ part, const int* __restrict__ bsum,
                        int* __restrict__ cursor, int n) {
    int i = blockIdx.x * blockDim.x + threadIdx.x;
    if (i >= n) return;
    int v = part[i] + bsum[i >> 8];
    part[i] = v;        // becomes row_start
    cursor[i] = v;
}

// ---------------- CSR fill: col[pos] = src, bucketed by dst ----------------

__global__ void k_fill(const int* __restrict__ ei, int* __restrict__ cursor,
                       int* __restrict__ col, int E) {
    int e = blockIdx.x * blockDim.x + threadIdx.x;
    if (e >= E) return;
    int dst = ei[E + e];
    int pos = atomicAdd(&cursor[dst], 1);
    col[pos] = ei[e];
}

// ---------------- W pre-transpose to bf16: wT[c][k] ----------------

__global__ void k_wprep(const float* __restrict__ Wg, const float* __restrict__ Wp,
                        unsigned short* __restrict__ wT) {
    int i = blockIdx.x * blockDim.x + threadIdx.x;
    if (i >= 96 * KPAD) return;
    int c = i / KPAD, k = i % KPAD;
    float v = 0.0f;
    if (k < IN_DIM) v = (c < 64) ? Wg[k * 64 + c] : Wp[k * 32 + (c - 64)];
    wT[i] = f2bf(v);
}

// ---------------- MFMA GEMM: xws = (x@W_gcn)*dis ; agg = xw*dis^2 ; zsem = x@W_ps + b_ps ----

#define BM 64
#define BK 64
#define APAD 72

__global__ __launch_bounds__(256) void k_gemm(
    const float* __restrict__ x, const unsigned short* __restrict__ wT,
    const float* __restrict__ bps, const float* __restrict__ dis,
    float* __restrict__ xws, float* __restrict__ agg, float* __restrict__ zsem,
    int n)
{
    __shared__ unsigned short a_lds[BM * APAD];   // 9216 B
    __shared__ unsigned short b_lds[96 * APAD];   // 13824 B

    int t = threadIdx.x;
    int row0 = blockIdx.x * BM;
    int w  = t >> 6;
    int l  = t & 63;
    int lm = l & 15;
    int lg = l >> 4;

    floatx4 acc[6] = {};

    for (int k0 = 0; k0 < IN_DIM; k0 += BK) {
        if (k0 + BK <= IN_DIM) {
            // fast A-stage: float4 loads (4B-aligned OK; row stride 1433 is odd)
            int c4 = t & 15;                 // 16B chunk within row
            int rb = t >> 4;                 // 16 rows per pass
            #pragma unroll
            for (int p = 0; p < 4; ++p) {
                int r = p * 16 + rb;
                int gr = row0 + r;
                short4v pv = {};
                if (gr < n) {
                    float4u v = *(const float4u*)&x[(long)gr * IN_DIM + k0 + 4 * c4];
                    pv.x = (short)f2bf(v.x); pv.y = (short)f2bf(v.y);
                    pv.z = (short)f2bf(v.z); pv.w = (short)f2bf(v.w);
                }
                *(short4v*)&a_lds[r * APAD + 4 * c4] = pv;
            }
        } else {
            // tail A-stage: scalar with per-element bounds
            int ar = t >> 6, ak = t & 63;
            #pragma unroll
            for (int rr = 0; rr < BM; rr += 4) {
                int r  = rr + ar;
                int gr = row0 + r;
                int gk = k0 + ak;
                float v = (gr < n && gk < IN_DIM) ? x[(long)gr * IN_DIM + gk] : 0.0f;
                a_lds[r * APAD + ak] = f2bf(v);
            }
        }
        // stage B from pre-converted wT (16B chunks, L2/L3-hit)
        #pragma unroll
        for (int it = 0; it < 3; ++it) {
            int idx = it * 256 + t;
            int c   = idx >> 3;
            int kc  = (idx & 7) * 8;
            short8 v = *(const short8*)&wT[c * KPAD + k0 + kc];
            *(short8*)&b_lds[c * APAD + kc] = v;
        }
        __syncthreads();
        #pragma unroll
        for (int h = 0; h < 2; ++h) {
            int koff = h * 32 + lg * 8;
            short8 af = *(const short8*)&a_lds[(w * 16 + lm) * APAD + koff];
            #pragma unroll
            for (int j = 0; j < 6; ++j) {
                short8 bf = *(const short8*)&b_lds[(j * 16 + lm) * APAD + koff];
                acc[j] = __builtin_amdgcn_mfma_f32_16x16x32_bf16(af, bf, acc[j], 0, 0, 0);
            }
        }
        __syncthreads();
    }

    // epilogue: C layout col=lane&15, row=(lane>>4)*4+reg
    #pragma unroll
    for (int r = 0; r < 4; ++r) {
        int grow = row0 + w * 16 + lg * 4 + r;
        if (grow >= n) continue;
        float d = dis[grow];
        #pragma unroll
        for (int j = 0; j < 6; ++j) {
            int c = j * 16 + lm;
            float v = acc[j][r];
            if (c < 64) {
                float s = v * d;                       // xw * dis[src], pre-scaled for pull
                xws[(long)grow * 64 + c] = s;
                agg[(long)grow * 64 + c] = s * d;      // self-loop: xw * dis^2
            } else {
                zsem[(long)grow * 32 + (c - 64)] = v + bps[c - 64];
            }
        }
    }
}

// ---------------- CSR pull: agg[dst] += dis[dst] * sum_{src in N(dst)} xws[src] ----------------
// one wave per dst; lane = feature; no atomics

__global__ __launch_bounds__(256) void k_pull(
    const int* __restrict__ row_start, const int* __restrict__ cnt,
    const int* __restrict__ col, const float* __restrict__ xws,
    const float* __restrict__ dis, float* __restrict__ agg, int n)
{
    int t = threadIdx.x;
    int dst = (blockIdx.x * 256 + t) >> 6;
    int lane = t & 63;
    if (dst >= n) return;
    int s = row_start[dst];
    int c = cnt[dst];
    float acc = 0.0f;
    for (int j0 = 0; j0 < c; j0 += 64) {
        int m = c - j0; if (m > 64) m = 64;
        int idx = (lane < m) ? col[s + j0 + lane] : 0;
        int j = 0;
        for (; j + 4 <= m; j += 4) {
            int s0 = __shfl(idx, j),     s1 = __shfl(idx, j + 1);
            int s2 = __shfl(idx, j + 2), s3 = __shfl(idx, j + 3);
            float v0 = xws[(long)s0 * 64 + lane];
            float v1 = xws[(long)s1 * 64 + lane];
            float v2 = xws[(long)s2 * 64 + lane];
            float v3 = xws[(long)s3 * 64 + lane];
            acc += (v0 + v1) + (v2 + v3);
        }
        for (; j < m; ++j) {
            int sj = __shfl(idx, j);
            acc += xws[(long)sj * 64 + lane];
        }
    }
    long o = (long)dst * 64 + lane;
    agg[o] += acc * dis[dst];
}

// ---------------- per-node head ----------------

__global__ __launch_bounds__(256) void k_head(
    const float* __restrict__ agg, const float* __restrict__ bgcn,
    const float* __restrict__ Wpt, const float* __restrict__ bpt,
    const float* __restrict__ Wcls, const float* __restrict__ bcls,
    const float* __restrict__ zsem,
    float* __restrict__ logits, float* __restrict__ anom, float* __restrict__ ztopo,
    int n)
{
    __shared__ float sW[H_TOPO * ALIGN];
    __shared__ float sC[ALIGN * NCLS];
    __shared__ float sbp[ALIGN], sbc[NCLS], sbg[H_TOPO];
    int t = threadIdx.x;
    for (int i = t; i < H_TOPO * ALIGN; i += 256) sW[i] = Wpt[i];
    for (int i = t; i < ALIGN * NCLS; i += 256) sC[i] = Wcls[i];
    if (t < ALIGN) sbp[t] = bpt[t];
    if (t < NCLS) sbc[t] = bcls[t];
    if (t < H_TOPO) sbg[t] = bgcn[t];
    __syncthreads();

    long node = (long)blockIdx.x * 256 + t;
    if (node >= n) return;

    float h[H_TOPO];
    const float* arow = agg + node * H_TOPO;
    #pragma unroll
    for (int k = 0; k < H_TOPO; ++k) h[k] = fmaxf(arow[k] + sbg[k], 0.0f);

    float z[ALIGN];
    #pragma unroll
    for (int j = 0; j < ALIGN; ++j) z[j] = sbp[j];
    #pragma unroll 4
    for (int k = 0; k < H_TOPO; ++k) {
        float hk = h[k];
        #pragma unroll
        for (int j = 0; j < ALIGN; ++j) z[j] += hk * sW[k * ALIGN + j];
    }

    float lg[NCLS];
    #pragma unroll
    for (int c = 0; c < NCLS; ++c) lg[c] = sbc[c];
    #pragma unroll
    for (int j = 0; j < ALIGN; ++j) {
        float zj = z[j];
        #pragma unroll
        for (int c = 0; c < NCLS; ++c) lg[c] += zj * sC[j * NCLS + c];
    }

    float ss = 0.0f;
    const float* zs = zsem + node * ALIGN;
    #pragma unroll
    for (int j = 0; j < ALIGN; ++j) { float d = z[j] - zs[j]; ss += d * d; }

    #pragma unroll
    for (int c = 0; c < NCLS; ++c) logits[node * NCLS + c] = lg[c];
    anom[node] = sqrtf(ss);
    #pragma unroll
    for (int j = 0; j < ALIGN; ++j) ztopo[node * ALIGN + j] = z[j];
}

// ---------------- launch ----------------

extern "C" void kernel_launch(void* const* d_in, const int* in_sizes, int n_in,
                              void* d_out, int out_size, void* d_ws, size_t ws_size,
                              hipStream_t stream) {
    const float* x   = (const float*)d_in[0];
    const int*   ei  = (const int*)d_in[1];
    const float* Wg  = (const float*)d_in[2];
    const float* bg  = (const float*)d_in[3];
    const float* Wpt = (const float*)d_in[4];
    const float* bpt = (const float*)d_in[5];
    const float* Wps = (const float*)d_in[6];
    const float* bps = (const float*)d_in[7];
    const float* Wc  = (const float*)d_in[8];
    const float* bc  = (const float*)d_in[9];

    int n = in_sizes[0] / IN_DIM;   // 50000
    int E = in_sizes[1] / 2;        // 1600000
    int nb = (n + 255) / 256;       // 196 scan blocks

    float* out    = (float*)d_out;
    float* logits = out;
    float* anom   = logits + (long)n * NCLS;
    float* ztopo  = anom + n;
    float* zsem   = ztopo + (long)n * ALIGN;

    // workspace layout (all chunks 16B-aligned for n=50000, E=1600000)
    float* ws   = (float*)d_ws;
    float* xws  = ws;                               // n*64 f
    float* agg  = xws + (long)n * H_TOPO;           // n*64 f
    float* dis  = agg + (long)n * H_TOPO;           // n f
    int* cnt       = (int*)(dis + n);               // n
    int* row_start = cnt + n;                       // n (scan1 partials -> starts)
    int* cursor    = row_start + n;                 // n
    int* bsum      = cursor + n;                    // 256
    int* col       = bsum + 256;                    // E
    unsigned short* wT = (unsigned short*)(col + E);// 96*KPAD bf16

    k_init  <<<nb, 256, 0, stream>>>(cnt, n);
    k_count <<<(E + 255) / 256, 256, 0, stream>>>(ei, cnt, E);
    k_rsqrt <<<nb, 256, 0, stream>>>(cnt, dis, n);
    k_scan1 <<<nb, 256, 0, stream>>>(cnt, row_start, bsum, n);
    k_scan2 <<<1, 256, 0, stream>>>(bsum, nb);
    k_scan3 <<<nb, 256, 0, stream>>>(row_start, bsum, cursor, n);
    k_fill  <<<(E + 255) / 256, 256, 0, stream>>>(ei, cursor, col, E);
    k_wprep <<<(96 * KPAD + 255) / 256, 256, 0, stream>>>(Wg, Wps, wT);
    k_gemm  <<<(n + BM - 1) / BM, 256, 0, stream>>>(x, wT, bps, dis, xws, agg, zsem, n);
    k_pull  <<<(n + 3) / 4, 256, 0, stream>>>(row_start, cnt, col, xws, dis, agg, n);
    k_head  <<<nb, 256, 0, stream>>>(agg, bg, Wpt, bpt, Wc, bc, zsem,
                                     logits, anom, ztopo, n);
}

// Round 4
// 698.797 us; speedup vs baseline: 2.6885x; 1.0320x over previous
//
#include <hip/hip_runtime.h>
#include <math.h>

#define IN_DIM 1433
#define KPAD 1472          // 23 * 64, zero-padded
#define H_TOPO 64
#define ALIGN 32
#define NCLS 7
#define NT 23              // ceil(1433/64), last tile has 25 valid k

typedef __attribute__((ext_vector_type(8))) short short8;
typedef __attribute__((ext_vector_type(4))) short short4v;
typedef __attribute__((ext_vector_type(4))) float floatx4;
typedef float float4u __attribute__((ext_vector_type(4), aligned(4)));   // 4B-aligned float4
typedef float float4a __attribute__((ext_vector_type(4), aligned(16)));  // 16B-aligned float4

__device__ inline unsigned short f2bf(float f) {
    union { float f; unsigned u; } v; v.f = f;
    unsigned r = v.u + 0x7FFF + ((v.u >> 16) & 1);   // round-to-nearest-even
    return (unsigned short)(r >> 16);
}

// ---------------- degree histogram ----------------

__global__ void k_count(const int* __restrict__ ei, int* __restrict__ cnt, int E) {
    int e = blockIdx.x * blockDim.x + threadIdx.x;
    if (e < E) atomicAdd(&cnt[ei[E + e]], 1);
}

// ---------------- exclusive scan of cnt -> row_start (+ rsqrt fused) ----------------

__global__ void k_scan1(const int* __restrict__ cnt, int* __restrict__ part,
                        int* __restrict__ bsum, int n) {
    __shared__ int s[256];
    int t = threadIdx.x;
    int i = blockIdx.x * 256 + t;
    int v = (i < n) ? cnt[i] : 0;
    s[t] = v;
    __syncthreads();
    #pragma unroll
    for (int off = 1; off < 256; off <<= 1) {
        int x = (t >= off) ? s[t - off] : 0;
        __syncthreads();
        s[t] += x;
        __syncthreads();
    }
    if (i < n) part[i] = s[t] - v;          // exclusive within block
    if (t == 255) bsum[blockIdx.x] = s[255];
}

__global__ void k_scan2(int* __restrict__ bsum, int nb) {
    __shared__ int s[256];
    int t = threadIdx.x;
    int v = (t < nb) ? bsum[t] : 0;
    s[t] = v;
    __syncthreads();
    #pragma unroll
    for (int off = 1; off < 256; off <<= 1) {
        int x = (t >= off) ? s[t - off] : 0;
        __syncthreads();
        s[t] += x;
        __syncthreads();
    }
    if (t < nb) bsum[t] = s[t] - v;         // exclusive block offsets
}

__global__ void k_scan3(int* __restrict__ part, const int* __restrict__ bsum,
                        const int* __restrict__ cnt, int* __restrict__ cursor,
                        float* __restrict__ dis, int n) {
    int i = blockIdx.x * blockDim.x + threadIdx.x;
    if (i >= n) return;
    int v = part[i] + bsum[i >> 8];
    part[i] = v;        // becomes row_start
    cursor[i] = v;
    dis[i] = rsqrtf(1.0f + (float)cnt[i]);  // +1 self-loop
}

// ---------------- CSR fill: col[pos] = src, bucketed by dst ----------------

__global__ void k_fill(const int* __restrict__ ei, int* __restrict__ cursor,
                       int* __restrict__ col, int E) {
    int e = blockIdx.x * blockDim.x + threadIdx.x;
    if (e >= E) return;
    int dst = ei[E + e];
    int pos = atomicAdd(&cursor[dst], 1);
    col[pos] = ei[e];
}

// ---------------- W pre-transpose to bf16: wT[c][k] ----------------

__global__ void k_wprep(const float* __restrict__ Wg, const float* __restrict__ Wp,
                        unsigned short* __restrict__ wT) {
    int i = blockIdx.x * blockDim.x + threadIdx.x;
    if (i >= 96 * KPAD) return;
    int c = i / KPAD, k = i % KPAD;
    float v = 0.0f;
    if (k < IN_DIM) v = (c < 64) ? Wg[k * 64 + c] : Wp[k * 32 + (c - 64)];
    wT[i] = f2bf(v);
}

// ---------------- MFMA GEMM (reg-prefetch pipeline):
//  xws = (x@W_gcn)*dis ; agg = xw*dis^2 ; zsem = x@W_ps + b_ps

#define BM 128
#define BK 64
#define APAD 72

__global__ __launch_bounds__(256) void k_gemm(
    const float* __restrict__ x, const unsigned short* __restrict__ wT,
    const float* __restrict__ bps, const float* __restrict__ dis,
    float* __restrict__ xws, float* __restrict__ agg, float* __restrict__ zsem,
    int n)
{
    __shared__ unsigned short a_lds[BM * APAD];   // 18432 B
    __shared__ unsigned short b_lds[96 * APAD];   // 13824 B

    int t = threadIdx.x;
    int row0 = blockIdx.x * BM;
    int w  = t >> 6;        // wave 0..3 -> rows w*32 .. w*32+31
    int l  = t & 63;
    int lm = l & 15;
    int lg = l >> 4;
    int c4 = t & 15;        // 16B chunk within row
    int rb = t >> 4;        // row within 16-row pass

    floatx4 acc[2][6] = {};
    float4u aPf[8];
    short8  bPf[3];

    auto load_tile = [&](int k0) {
        if (k0 + BK <= IN_DIM) {
            #pragma unroll
            for (int p = 0; p < 8; ++p) {
                int gr = row0 + p * 16 + rb;
                float4u v = {};
                if (gr < n) v = *(const float4u*)&x[(long)gr * IN_DIM + k0 + 4 * c4];
                aPf[p] = v;
            }
        } else {
            #pragma unroll
            for (int p = 0; p < 8; ++p) {
                int gr = row0 + p * 16 + rb;
                float4u v = {};
                if (gr < n) {
                    #pragma unroll
                    for (int q = 0; q < 4; ++q) {
                        int gk = k0 + 4 * c4 + q;
                        v[q] = (gk < IN_DIM) ? x[(long)gr * IN_DIM + gk] : 0.0f;
                    }
                }
                aPf[p] = v;
            }
        }
        #pragma unroll
        for (int it = 0; it < 3; ++it) {
            int idx = it * 256 + t;
            int c = idx >> 3, kc = (idx & 7) * 8;
            bPf[it] = *(const short8*)&wT[c * KPAD + k0 + kc];
        }
    };
    auto store_tile = [&]() {
        #pragma unroll
        for (int p = 0; p < 8; ++p) {
            short4v pv;
            pv.x = (short)f2bf(aPf[p].x); pv.y = (short)f2bf(aPf[p].y);
            pv.z = (short)f2bf(aPf[p].z); pv.w = (short)f2bf(aPf[p].w);
            *(short4v*)&a_lds[(p * 16 + rb) * APAD + 4 * c4] = pv;
        }
        #pragma unroll
        for (int it = 0; it < 3; ++it) {
            int idx = it * 256 + t;
            int c = idx >> 3, kc = (idx & 7) * 8;
            *(short8*)&b_lds[c * APAD + kc] = bPf[it];
        }
    };

    load_tile(0);
    store_tile();
    __syncthreads();

    for (int kt = 0; kt < NT; ++kt) {
        if (kt + 1 < NT) load_tile((kt + 1) * BK);   // global loads in flight over MFMA
        #pragma unroll
        for (int h = 0; h < 2; ++h) {
            int koff = h * 32 + lg * 8;
            short8 a0 = *(const short8*)&a_lds[(w * 32 + lm) * APAD + koff];
            short8 a1 = *(const short8*)&a_lds[(w * 32 + 16 + lm) * APAD + koff];
            #pragma unroll
            for (int j = 0; j < 6; ++j) {
                short8 bf = *(const short8*)&b_lds[(j * 16 + lm) * APAD + koff];
                acc[0][j] = __builtin_amdgcn_mfma_f32_16x16x32_bf16(a0, bf, acc[0][j], 0, 0, 0);
                acc[1][j] = __builtin_amdgcn_mfma_f32_16x16x32_bf16(a1, bf, acc[1][j], 0, 0, 0);
            }
        }
        __syncthreads();                 // all waves done reading LDS
        if (kt + 1 < NT) {
            store_tile();                // write prefetched tile
            __syncthreads();
        }
    }

    // epilogue: C layout col=lane&15, row=(lane>>4)*4+reg
    #pragma unroll
    for (int mt = 0; mt < 2; ++mt) {
        #pragma unroll
        for (int r = 0; r < 4; ++r) {
            int grow = row0 + w * 32 + mt * 16 + lg * 4 + r;
            if (grow >= n) continue;
            float d = dis[grow];
            #pragma unroll
            for (int j = 0; j < 6; ++j) {
                int c = j * 16 + lm;
                float v = acc[mt][j][r];
                if (c < 64) {
                    float s = v * d;                       // xw * dis[src], pre-scaled
                    xws[(long)grow * 64 + c] = s;
                    agg[(long)grow * 64 + c] = s * d;      // self-loop: xw * dis^2
                } else {
                    zsem[(long)grow * 32 + (c - 64)] = v + bps[c - 64];
                }
            }
        }
    }
}

// ---------------- CSR pull: agg[dst] += dis[dst] * sum_{src in N(dst)} xws[src] ----
// one wave per dst; lane = (neighbor-slot ng, feature-quad f4); float4 gathers

__global__ __launch_bounds__(256) void k_pull(
    const int* __restrict__ row_start, const int* __restrict__ cnt,
    const int* __restrict__ col, const float* __restrict__ xws,
    const float* __restrict__ dis, float* __restrict__ agg, int n)
{
    int t = threadIdx.x;
    int dst = (blockIdx.x * 256 + t) >> 6;
    int lane = t & 63;
    int ng = lane >> 4;     // neighbor slot 0..3
    int f4 = lane & 15;     // feature quad
    if (dst >= n) return;
    int s = row_start[dst];
    int c = cnt[dst];
    floatx4 acc = {};
    for (int j0 = 0; j0 < c; j0 += 64) {
        int m = c - j0; if (m > 64) m = 64;
        int idx = (lane < m) ? col[s + j0 + lane] : -1;
        for (int j = 0; j < m; j += 4) {
            int sj = __shfl(idx, j + ng);          // j+ng <= 63 always
            if (sj >= 0) {
                float4a v = *(const float4a*)&xws[(long)sj * 64 + f4 * 4];
                acc += v;
            }
        }
    }
    // reduce across the 4 neighbor slots
    #pragma unroll
    for (int q = 0; q < 4; ++q) {
        acc[q] += __shfl_xor(acc[q], 16);
        acc[q] += __shfl_xor(acc[q], 32);
    }
    if (ng == 0) {
        float dd = dis[dst];
        float4a* po = (float4a*)&agg[(long)dst * 64 + f4 * 4];
        float4a o = *po;                            // self-loop term already there
        o.x += acc.x * dd; o.y += acc.y * dd; o.z += acc.z * dd; o.w += acc.w * dd;
        *po = o;
    }
}

// ---------------- per-node head ----------------

__global__ __launch_bounds__(256) void k_head(
    const float* __restrict__ agg, const float* __restrict__ bgcn,
    const float* __restrict__ Wpt, const float* __restrict__ bpt,
    const float* __restrict__ Wcls, const float* __restrict__ bcls,
    const float* __restrict__ zsem,
    float* __restrict__ logits, float* __restrict__ anom, float* __restrict__ ztopo,
    int n)
{
    __shared__ float sW[H_TOPO * ALIGN];
    __shared__ float sC[ALIGN * NCLS];
    __shared__ float sbp[ALIGN], sbc[NCLS], sbg[H_TOPO];
    int t = threadIdx.x;
    for (int i = t; i < H_TOPO * ALIGN; i += 256) sW[i] = Wpt[i];
    for (int i = t; i < ALIGN * NCLS; i += 256) sC[i] = Wcls[i];
    if (t < ALIGN) sbp[t] = bpt[t];
    if (t < NCLS) sbc[t] = bcls[t];
    if (t < H_TOPO) sbg[t] = bgcn[t];
    __syncthreads();

    long node = (long)blockIdx.x * 256 + t;
    if (node >= n) return;

    float h[H_TOPO];
    const float* arow = agg + node * H_TOPO;
    #pragma unroll
    for (int k = 0; k < H_TOPO; ++k) h[k] = fmaxf(arow[k] + sbg[k], 0.0f);

    float z[ALIGN];
    #pragma unroll
    for (int j = 0; j < ALIGN; ++j) z[j] = sbp[j];
    #pragma unroll 4
    for (int k = 0; k < H_TOPO; ++k) {
        float hk = h[k];
        #pragma unroll
        for (int j = 0; j < ALIGN; ++j) z[j] += hk * sW[k * ALIGN + j];
    }

    float lg[NCLS];
    #pragma unroll
    for (int c = 0; c < NCLS; ++c) lg[c] = sbc[c];
    #pragma unroll
    for (int j = 0; j < ALIGN; ++j) {
        float zj = z[j];
        #pragma unroll
        for (int c = 0; c < NCLS; ++c) lg[c] += zj * sC[j * NCLS + c];
    }

    float ss = 0.0f;
    const float* zs = zsem + node * ALIGN;
    #pragma unroll
    for (int j = 0; j < ALIGN; ++j) { float d = z[j] - zs[j]; ss += d * d; }

    #pragma unroll
    for (int c = 0; c < NCLS; ++c) logits[node * NCLS + c] = lg[c];
    anom[node] = sqrtf(ss);
    #pragma unroll
    for (int j = 0; j < ALIGN; ++j) ztopo[node * ALIGN + j] = z[j];
}

// ---------------- launch ----------------

extern "C" void kernel_launch(void* const* d_in, const int* in_sizes, int n_in,
                              void* d_out, int out_size, void* d_ws, size_t ws_size,
                              hipStream_t stream) {
    const float* x   = (const float*)d_in[0];
    const int*   ei  = (const int*)d_in[1];
    const float* Wg  = (const float*)d_in[2];
    const float* bg  = (const float*)d_in[3];
    const float* Wpt = (const float*)d_in[4];
    const float* bpt = (const float*)d_in[5];
    const float* Wps = (const float*)d_in[6];
    const float* bps = (const float*)d_in[7];
    const float* Wc  = (const float*)d_in[8];
    const float* bc  = (const float*)d_in[9];

    int n = in_sizes[0] / IN_DIM;   // 50000
    int E = in_sizes[1] / 2;        // 1600000
    int nb = (n + 255) / 256;       // 196

    float* out    = (float*)d_out;
    float* logits = out;
    float* anom   = logits + (long)n * NCLS;
    float* ztopo  = anom + n;
    float* zsem   = ztopo + (long)n * ALIGN;

    // workspace layout (16B-aligned chunks for n=50000, E=1600000)
    float* ws   = (float*)d_ws;
    float* xws  = ws;                               // n*64 f
    float* agg  = xws + (long)n * H_TOPO;           // n*64 f
    float* dis  = agg + (long)n * H_TOPO;           // n f
    int* cnt       = (int*)(dis + n);               // n
    int* row_start = cnt + n;                       // n
    int* cursor    = row_start + n;                 // n
    int* bsum      = cursor + n;                    // 256
    int* col       = bsum + 256;                    // E
    unsigned short* wT = (unsigned short*)(col + E);// 96*KPAD bf16

    hipMemsetAsync(cnt, 0, (size_t)n * sizeof(int), stream);
    k_count <<<(E + 255) / 256, 256, 0, stream>>>(ei, cnt, E);
    k_scan1 <<<nb, 256, 0, stream>>>(cnt, row_start, bsum, n);
    k_scan2 <<<1, 256, 0, stream>>>(bsum, nb);
    k_scan3 <<<nb, 256, 0, stream>>>(row_start, bsum, cnt, cursor, dis, n);
    k_fill  <<<(E + 255) / 256, 256, 0, stream>>>(ei, cursor, col, E);
    k_wprep <<<(96 * KPAD + 255) / 256, 256, 0, stream>>>(Wg, Wps, wT);
    k_gemm  <<<(n + BM - 1) / BM, 256, 0, stream>>>(x, wT, bps, dis, xws, agg, zsem, n);
    k_pull  <<<(n + 3) / 4, 256, 0, stream>>>(row_start, cnt, col, xws, dis, agg, n);
    k_head  <<<nb, 256, 0, stream>>>(agg, bg, Wpt, bpt, Wc, bc, zsem,
                                     logits, anom, ztopo, n);
}